// Round 7
// baseline (203.468 us; speedup 1.0000x reference)
//
#include <hip/hip_runtime.h>
#include <hip/hip_bf16.h>

// Fused MHA, B=8, S=1024, H=8, DK=128, D=1024, fp32 in/out, bf16 MFMA compute.
// convert(weights only) -> QKV proj (256x128 3-buf 2-phase counted-vmcnt GEMM,
// f32 A reg-staged with fused bf16 convert, z=3 merged, XCD swizzle, V^T epilogue)
// -> flash attn (swapped-QK in-lane softmax, cvt_pk, XCD swizzle, fused arrange)
// -> out proj (same GEMM, bf16 A via global_load_lds, fp32 out).

typedef __attribute__((ext_vector_type(8))) __bf16 bf16x8;
typedef __attribute__((ext_vector_type(4))) float f32x4;

#define DEV static __device__ __forceinline__

DEV float exp2v(float x) { return __builtin_amdgcn_exp2f(x); }

DEV unsigned short f2bf(float f) {
  union { float f; unsigned int u; } c; c.f = f;
  unsigned int u = c.u + 0x7fffu + ((c.u >> 16) & 1u);
  return (unsigned short)(u >> 16);
}

DEV unsigned cvtpk(float a, float b) {
  unsigned r;
  asm("v_cvt_pk_bf16_f32 %0, %1, %2" : "=v"(r) : "v"(a), "v"(b));
  return r;
}

DEV void gload16(const void* g, void* l) {
  __builtin_amdgcn_global_load_lds((const __attribute__((address_space(1))) void*)g,
                                   (__attribute__((address_space(3))) void*)l, 16, 0, 0);
}

#define LGKM0 do { asm volatile("s_waitcnt lgkmcnt(0)" ::: "memory"); \
                   __builtin_amdgcn_sched_barrier(0); } while (0)
#define BAR   __builtin_amdgcn_s_barrier()
#define VMC(n) asm volatile("s_waitcnt vmcnt(" #n ")" ::: "memory")

// ---------------- convert: weights fp32->bf16 (4 MiB elems) ----------------
DEV void cv4(const float* __restrict__ s, unsigned short* __restrict__ d, int i) {
  const float4 a = *(const float4*)(s + i);
  ushort4 o;
  o.x = f2bf(a.x); o.y = f2bf(a.y); o.z = f2bf(a.z); o.w = f2bf(a.w);
  *(ushort4*)(d + i) = o;
}

__global__ __launch_bounds__(256) void convert_w(
    const float* __restrict__ wq, const float* __restrict__ wk,
    const float* __restrict__ wv, const float* __restrict__ wo,
    unsigned short* __restrict__ wb)
{
  const int i = (blockIdx.x * 256 + threadIdx.x) * 4;   // 4096 blocks x 1024 elems
  const int which = i >> 20, off = i & 1048575;
  const float* s = which == 0 ? wq : which == 1 ? wk : which == 2 ? wv : wo;
  cv4(s, wb + (which << 20), off);
}

// ---------------- unified 256x128 3-buffer 2-phase GEMM ----------------
// C[m,n] = sum_k A[m,k]*Bt[n,k] + bias[n]. K=1024 = 16 BK=64 tiles.
// 512 thr = 8 waves (4M x 2N), per-wave 64x64 (acc[4][4]).
// LDS 144 KiB: A 3buf x 256x128B @0; B 3buf x 128x128B @98304.
// XOR swizzle (16B chunk ^ (row&7)<<4) on both write and read sides.
// Per tile: phX {rdB8+rdA4 | stage | BAR | lgkm0 | mm16 | BAR},
//           phY {rdA4 | stage | BAR | lgkm0 | mm16 | tile-gate vmcnt | BAR}.
// Tile t: computes buf[t%3]; stages tile t+2 into buf[(t+2)%3];
// AMODE 0 additionally writes A(t+1) (reg-staged f32->bf16) into buf[(t+1)%3].
// AMODE 0: QKV (z: 0=Q scaled, 1=K, 2=V^T packed).  AMODE 1: fp32 out proj.
template<int AMODE>
__global__ __launch_bounds__(512, 2) void gemm3b(
    const float* __restrict__ Aq, const float* __restrict__ Ak,
    const float* __restrict__ Av, const unsigned short* __restrict__ Abf,
    const unsigned short* __restrict__ wbase,
    const float* __restrict__ bq, const float* __restrict__ bk,
    const float* __restrict__ bv,
    unsigned short* __restrict__ Qp, unsigned short* __restrict__ Kp,
    unsigned short* __restrict__ VTp, float* __restrict__ fout)
{
  __shared__ __align__(16) char LDS[147456];
  int z, mt, nt;
  if (AMODE == 0) {        // 768 blocks = 8 XCD x 96
    const int swz = (blockIdx.x & 7) * 96 + (blockIdx.x >> 3);
    z = swz >> 8; const int rem = swz & 255; mt = rem >> 3; nt = rem & 7;
  } else {                 // 256 blocks = 8 XCD x 32
    const int swz = (blockIdx.x & 7) * 32 + (blockIdx.x >> 3);
    z = 0; mt = swz >> 3; nt = swz & 7;
  }
  const int m0 = mt * 256, n0 = nt * 128;
  const float* Af = (AMODE == 0) ? (z == 0 ? Aq : z == 1 ? Ak : Av) : nullptr;
  const unsigned short* Bg = wbase + ((size_t)(AMODE == 0 ? z : 0) << 20);
  const float* bias = (AMODE == 0) ? (z == 0 ? bq : z == 1 ? bk : bv) : bq;

  const int tid = threadIdx.x, lane = tid & 63, w = tid >> 6;
  const int wm = w >> 1, wn = w & 1;
  const int g = lane >> 4, ln = lane & 15;

  const f32x4 fzero = {0.f, 0.f, 0.f, 0.f};
  f32x4 acc[4][4];
#pragma unroll
  for (int i = 0; i < 4; i++)
#pragma unroll
    for (int j = 0; j < 4; j++) acc[i][j] = fzero;

  bf16x8 afr[2][2], bfr[4][2];

  // B stage: bf16 gload16, linear dest + inverse-swizzled source
  auto SB = [&](int buf, int k0) {
    char* base = LDS + 98304 + buf * 16384 + w * 2048;
#pragma unroll
    for (int j2 = 0; j2 < 2; ++j2) {
      const int o = w * 2048 + j2 * 1024 + lane * 16;
      const int row = o >> 7, cb = o & 127;
      gload16(Bg + (size_t)(n0 + row) * 1024 + k0 + ((cb ^ ((row & 7) << 4)) >> 1),
              base + j2 * 1024);
    }
  };
  // A stage (AMODE 1): bf16 gload16
  auto SA = [&](int buf, int hf, int k0) {
    char* base = LDS + buf * 32768 + hf * 16384 + w * 2048;
#pragma unroll
    for (int j2 = 0; j2 < 2; ++j2) {
      const int o = w * 2048 + j2 * 1024 + lane * 16;
      const int row = o >> 7, cb = o & 127;
      gload16(Abf + (size_t)(m0 + hf * 128 + row) * 1024 + k0 + ((cb ^ ((row & 7) << 4)) >> 1),
              base + j2 * 1024);
    }
  };

  // A reg-stage map (AMODE 0): thread covers row=tid/4, 16 f32 at col (tid&3)*16
  const int arow = tid >> 2;
  const int acol = (tid & 3) << 4;
  const int wsw = (arow & 7) << 4;
  const int wc0 = ((tid & 3) * 32) ^ wsw;        // swizzled byte of chunk 0
  const int wc1 = ((tid & 3) * 32 + 16) ^ wsw;   // swizzled byte of chunk 1

#define LA4(d0, d1, d2, d3, hf, k0) do { \
    const float* _s = Af + (size_t)(m0 + (hf) * 128 + arow) * 1024 + (k0) + acol; \
    d0 = *(const float4*)(_s); d1 = *(const float4*)(_s + 4); \
    d2 = *(const float4*)(_s + 8); d3 = *(const float4*)(_s + 12); } while (0)

#define WA4(buf, hf, s0, s1, s2, s3) do { \
    char* _d = LDS + (buf) * 32768 + (hf) * 16384 + arow * 128; \
    uint4 _p0, _p1; \
    _p0.x = cvtpk(s0.x, s0.y); _p0.y = cvtpk(s0.z, s0.w); \
    _p0.z = cvtpk(s1.x, s1.y); _p0.w = cvtpk(s1.z, s1.w); \
    _p1.x = cvtpk(s2.x, s2.y); _p1.y = cvtpk(s2.z, s2.w); \
    _p1.z = cvtpk(s3.x, s3.y); _p1.w = cvtpk(s3.z, s3.w); \
    *(uint4*)(_d + wc0) = _p0; *(uint4*)(_d + wc1) = _p1; } while (0)

  auto rdA = [&](int buf, int q) {
#pragma unroll
    for (int p = 0; p < 2; ++p) {
      const int row = wm * 64 + (2 * q + p) * 16 + ln;
      const int sw = (row & 7) << 4;
#pragma unroll
      for (int kc = 0; kc < 2; ++kc)
        afr[p][kc] = *(const bf16x8*)(LDS + buf * 32768 + row * 128 + ((kc * 64 + g * 16) ^ sw));
    }
  };
  auto rdB = [&](int buf) {
#pragma unroll
    for (int nf = 0; nf < 4; ++nf) {
      const int row = wn * 64 + nf * 16 + ln;
      const int sw = (row & 7) << 4;
#pragma unroll
      for (int kc = 0; kc < 2; ++kc)
        bfr[nf][kc] = *(const bf16x8*)(LDS + 98304 + buf * 16384 + row * 128 + ((kc * 64 + g * 16) ^ sw));
    }
  };
  auto mm = [&](int q) {
    __builtin_amdgcn_s_setprio(1);
#pragma unroll
    for (int p = 0; p < 2; ++p)
#pragma unroll
      for (int nf = 0; nf < 4; ++nf)
#pragma unroll
        for (int kc = 0; kc < 2; ++kc)
          acc[2 * q + p][nf] =
              __builtin_amdgcn_mfma_f32_16x16x32_bf16(afr[p][kc], bfr[nf][kc],
                                                      acc[2 * q + p][nf], 0, 0, 0);
    __builtin_amdgcn_s_setprio(0);
  };

  // two named reg sets: set0 = aA..aD (h0:aA,aB? no — h0 = aA..aB? we use 4
  // float4 per half: set0 h0 = a00..a03, h1 = a04..a07; set1 = a10.. )
  float4 a00, a01, a02, a03, a04, a05, a06, a07;   // set0: h0 = a00..03, h1 = a04..07
  float4 a10, a11, a12, a13, a14, a15, a16, a17;   // set1

  // ---- prologue: tiles 0,1 staged; steady-state issue order ----
  if (AMODE == 0) {
    LA4(a00, a01, a02, a03, 0, 0);   // tile0 h0 -> set0
    LA4(a04, a05, a06, a07, 1, 0);   // tile0 h1
    SB(0, 0);                        // B(0)
    LA4(a10, a11, a12, a13, 0, 64);  // tile1 h0 -> set1
    LA4(a14, a15, a16, a17, 1, 64);  // tile1 h1
    SB(1, 64);                       // B(1)
    WA4(0, 0, a00, a01, a02, a03);   // A(0) h0 (compiler inserts load waits)
    WA4(0, 1, a04, a05, a06, a07);   // A(0) h1
    VMC(10);                         // B(0) arrived (younger: LA(1)x8 + SB(1)x2)
  } else {
    SA(0, 0, 0); SA(0, 1, 0);
    SB(0, 0);
    SA(1, 0, 64); SA(1, 1, 64);
    SB(1, 64);
    VMC(6);                          // A(0)+B(0) arrived (younger: SA(1)x4 + SB(1)x2)
  }
  LGKM0; BAR;

  // ---- tile loop: t computes buf br; stages t+2 -> bw; writes A(t+1) -> bn ----
#define TILE(t, L0, L1, L2, L3, L4, L5, L6, L7, W0, W1, W2, W3, W4, W5, W6, W7, br, bn, bw) \
  do { \
    const int _kL = ((t) + 2) << 6; \
    const bool _ld = (t) < 14, _wr = (t) < 15; \
    /* phX */ \
    rdB(br); rdA(br, 0); \
    if (AMODE == 0) { \
      if (_ld) LA4(L0, L1, L2, L3, 0, _kL); \
      if (_wr) WA4(bn, 0, W0, W1, W2, W3); \
    } else { \
      if (_ld) SA(bw, 0, _kL); \
    } \
    BAR; LGKM0; mm(0); BAR; \
    /* phY */ \
    rdA(br, 1); \
    if (AMODE == 0) { \
      if (_ld) LA4(L4, L5, L6, L7, 1, _kL); \
      if (_wr) WA4(bn, 1, W4, W5, W6, W7); \
    } else { \
      if (_ld) SA(bw, 1, _kL); \
    } \
    if (_ld) SB(bw, _kL); \
    BAR; LGKM0; mm(1); \
    if (_ld) { if (AMODE == 0) VMC(10); else VMC(6); } \
    else if ((t) < 15) VMC(0); \
    BAR; \
  } while (0)

  int br = 0, bn = 1, bw = 2;
  for (int t2 = 0; t2 < 16; t2 += 2) {
    // even tile: load -> set0, write-from set1
    TILE(t2, a00, a01, a02, a03, a04, a05, a06, a07,
             a10, a11, a12, a13, a14, a15, a16, a17, br, bn, bw);
    { const int x = br; br = bn; bn = bw; bw = x; }
    // odd tile: load -> set1, write-from set0
    TILE(t2 + 1, a10, a11, a12, a13, a14, a15, a16, a17,
                 a00, a01, a02, a03, a04, a05, a06, a07, br, bn, bw);
    { const int x = br; br = bn; bn = bw; bw = x; }
  }
#undef TILE
#undef LA4
#undef WA4

  // ---- epilogue ----
  const float QS = 0.12751743f;   // 1/sqrt(128)*log2(e)
#pragma unroll
  for (int mf = 0; mf < 4; ++mf)
#pragma unroll
    for (int nf = 0; nf < 4; ++nf) {
      const int m = m0 + wm * 64 + mf * 16 + g * 4;
      const int n = n0 + wn * 64 + nf * 16 + ln;
      const float bn_ = bias[n];
      if (AMODE == 1) {
#pragma unroll
        for (int r = 0; r < 4; ++r)
          fout[(size_t)(m + r) * 1024 + n] = acc[mf][nf][r] + bn_;
      } else if (z == 0) {
#pragma unroll
        for (int r = 0; r < 4; ++r)
          Qp[(size_t)(m + r) * 1024 + n] = f2bf((acc[mf][nf][r] + bn_) * QS);
      } else if (z == 1) {
#pragma unroll
        for (int r = 0; r < 4; ++r)
          Kp[(size_t)(m + r) * 1024 + n] = f2bf(acc[mf][nf][r] + bn_);
      } else {
        const int b = m >> 10, s0 = m & 1023;   // n = h*128+dk (global out-dim)
        uint2 pk;
        pk.x = cvtpk(acc[mf][nf][0] + bn_, acc[mf][nf][1] + bn_);
        pk.y = cvtpk(acc[mf][nf][2] + bn_, acc[mf][nf][3] + bn_);
        *(uint2*)(VTp + (((size_t)(b * 1024 + n)) << 10) + s0) = pk;
      }
    }
}

// ---------------- flash attention + fused attn_arrange (+zero pad) ----------------
__global__ __launch_bounds__(256) void attn_kernel(
    const unsigned short* __restrict__ Qp, const unsigned short* __restrict__ Kp,
    const unsigned short* __restrict__ VT, const int* __restrict__ cfg,
    unsigned short* __restrict__ ret)
{
  __shared__ __align__(16) unsigned short Ks[2][64 * 128];
  __shared__ __align__(16) unsigned short Vs[2][128 * 64];
  __shared__ __align__(16) unsigned short Ps[4 * 16 * 64];
  const int bx = blockIdx.x;
  const int qb = bx >> 6, bh = bx & 63, b = bh >> 3, h = bh & 7;
  const int tid = threadIdx.x, lane = tid & 63, w = tid >> 6;
  const int g = lane >> 4, ln = lane & 15;
  const int q0 = qb * 64;
  const f32x4 fzero = {0.f, 0.f, 0.f, 0.f};

  bf16x8 qf[4];
  {
    const unsigned short* qrow = Qp + ((size_t)(b * 1024 + q0 + w * 16 + ln)) * 1024 + h * 128;
#pragma unroll
    for (int kc = 0; kc < 4; kc++) qf[kc] = *(const bf16x8*)(qrow + kc * 32 + g * 8);
  }
  float m_run = -1e30f, l_run = 0.f;
  f32x4 o_acc[8];
#pragma unroll
  for (int i = 0; i < 8; i++) o_acc[i] = fzero;

  auto stage = [&](int buf, int kv0) {
#pragma unroll
    for (int i = 0; i < 4; ++i) {
      const int obase = i * 4096 + w * 1024;
      const int o = obase + lane * 16;
      {
        const int r = o >> 8, cb = o & 255;
        const int cs = cb ^ ((r & 7) << 4);
        gload16(Kp + ((size_t)(b * 1024 + kv0 + r)) * 1024 + h * 128 + (cs >> 1),
                (char*)Ks + buf * 16384 + obase);
      }
      {
        const int r = o >> 7, cb = o & 127;
        const int cs = cb ^ ((r & 7) << 4);
        gload16(VT + ((size_t)((b * 8 + h) * 128 + r)) * 1024 + kv0 + (cs >> 1),
                (char*)Vs + buf * 16384 + obase);
      }
    }
  };

  stage(0, 0);
  asm volatile("s_waitcnt vmcnt(0)" ::: "memory");
  __syncthreads();

  int cur = 0;
  for (int t = 0; t < 16; ++t) {
    if (t < 15) stage(cur ^ 1, (t + 1) * 64);

    f32x4 sc[4];
    __builtin_amdgcn_s_setprio(1);
#pragma unroll
    for (int nb = 0; nb < 4; ++nb) {
      sc[nb] = fzero;
      const int rr = nb * 16 + ln;
      const int sw = (rr & 7) << 4;
#pragma unroll
      for (int kc = 0; kc < 4; ++kc) {
        const bf16x8 kf = *(const bf16x8*)((const char*)Ks + cur * 16384 + rr * 256 +
                                           (((kc * 32 + g * 8) << 1) ^ sw));
        sc[nb] = __builtin_amdgcn_mfma_f32_16x16x32_bf16(kf, qf[kc], sc[nb], 0, 0, 0);
      }
    }
    __builtin_amdgcn_s_setprio(0);

    float mnb[4];
#pragma unroll
    for (int nb = 0; nb < 4; ++nb)
      mnb[nb] = fmaxf(fmaxf(sc[nb][0], sc[nb][1]), fmaxf(sc[nb][2], sc[nb][3]));
    float pmax = fmaxf(fmaxf(mnb[0], mnb[1]), fmaxf(mnb[2], mnb[3]));
    pmax = fmaxf(pmax, __shfl_xor(pmax, 16));
    pmax = fmaxf(pmax, __shfl_xor(pmax, 32));
    if (__any(pmax > m_run + 11.5f)) {
      const float mnew = fmaxf(m_run, pmax);
      const float alpha = exp2v(m_run - mnew);
      l_run *= alpha;
      m_run = mnew;
      float ar[4];
#pragma unroll
      for (int r = 0; r < 4; ++r)
        ar[r] = __shfl(alpha, (lane & 48) | (((lane >> 4) & 3) << 2) | r);
#pragma unroll
      for (int i = 0; i < 8; i++)
#pragma unroll
        for (int r = 0; r < 4; r++) o_acc[i][r] *= ar[r];
    }
    float sum = 0.f;
    float pvv[16];
#pragma unroll
    for (int nb = 0; nb < 4; ++nb)
#pragma unroll
      for (int r = 0; r < 4; ++r) {
        const float p = exp2v(sc[nb][r] - m_run);
        pvv[nb * 4 + r] = p; sum += p;
      }
    l_run += sum;

    {
      char* pbase = (char*)Ps + w * 2048 + ln * 128;
#pragma unroll
      for (int nb = 0; nb < 4; ++nb) {
        uint2 pk;
        pk.x = cvtpk(pvv[nb * 4 + 0], pvv[nb * 4 + 1]);
        pk.y = cvtpk(pvv[nb * 4 + 2], pvv[nb * 4 + 3]);
        *(uint2*)(pbase + (((16 * nb + 4 * g) << 1) ^ ((ln & 7) << 4))) = pk;
      }
    }
    bf16x8 pf[2];
#pragma unroll
    for (int kc = 0; kc < 2; kc++)
      pf[kc] = *(const bf16x8*)((const char*)Ps + w * 2048 + ln * 128 +
                                (((kc * 32 + g * 8) << 1) ^ ((ln & 7) << 4)));

    __builtin_amdgcn_s_setprio(1);
#pragma unroll
    for (int nb2 = 0; nb2 < 8; ++nb2) {
      const int rr = nb2 * 16 + ln;
      const int sw = (rr & 7) << 4;
#pragma unroll
      for (int kc = 0; kc < 2; ++kc) {
        const bf16x8 vf = *(const bf16x8*)((const char*)Vs + cur * 16384 + rr * 128 +
                                           (((kc * 32 + g * 8) << 1) ^ sw));
        o_acc[nb2] = __builtin_amdgcn_mfma_f32_16x16x32_bf16(pf[kc], vf, o_acc[nb2], 0, 0, 0);
      }
    }
    __builtin_amdgcn_s_setprio(0);

    if (t < 15) {
      asm volatile("s_waitcnt vmcnt(0)" ::: "memory");
      __syncthreads();
    }
    cur ^= 1;
  }

  l_run += __shfl_xor(l_run, 16);
  l_run += __shfl_xor(l_run, 32);
  float rl[4];
#pragma unroll
  for (int r = 0; r < 4; ++r)
    rl[r] = 1.0f / __shfl(l_run, (lane & 48) | (((lane >> 4) & 3) << 2) | r);
  const int d_b = 32 * (cfg[b] + 1);
  const int zw = 128 - d_b;
  const size_t rowbase = (size_t)(b * 1024 + q0 + w * 16 + g * 4);
#pragma unroll
  for (int nb2 = 0; nb2 < 8; ++nb2) {
    const int dk = nb2 * 16 + ln;
    if (dk < d_b) {
#pragma unroll
      for (int r = 0; r < 4; r++)
        ret[(rowbase + r) * 1024 + h * d_b + dk] = f2bf(o_acc[nb2][r] * rl[r]);
    } else {
#pragma unroll
      for (int r = 0; r < 4; r++)
        ret[(rowbase + r) * 1024 + 8 * d_b + h * zw + (dk - d_b)] = 0;
    }
  }
}

// ---------------- launch ----------------
extern "C" void kernel_launch(void* const* d_in, const int* in_sizes, int n_in,
                              void* d_out, int out_size, void* d_ws, size_t ws_size,
                              hipStream_t stream)
{
  (void)in_sizes; (void)n_in; (void)out_size; (void)ws_size;
  const float* q   = (const float*)d_in[0];
  const float* k   = (const float*)d_in[1];
  const float* v   = (const float*)d_in[2];
  const int*   cfg = (const int*)d_in[3];
  const float* Wq  = (const float*)d_in[4];  const float* bq = (const float*)d_in[5];
  const float* Wk  = (const float*)d_in[6];  const float* bk = (const float*)d_in[7];
  const float* Wv  = (const float*)d_in[8];  const float* bv = (const float*)d_in[9];
  const float* Wo  = (const float*)d_in[10]; const float* bo = (const float*)d_in[11];

  const size_t X  = 8192ull * 1024ull;
  const size_t WN = 1024ull * 1024ull;
  char* p = (char*)d_ws;
  unsigned short* wb  = (unsigned short*)p; p += 4 * WN * 2;
  unsigned short* Qp  = (unsigned short*)p; p += X * 2;
  unsigned short* Kp  = (unsigned short*)p; p += X * 2;
  unsigned short* VTp = (unsigned short*)p; p += X * 2;
  unsigned short* ret = (unsigned short*)p; p += X * 2;

  convert_w<<<dim3(4096), dim3(256), 0, stream>>>(Wq, Wk, Wv, Wo, wb);

  gemm3b<0><<<dim3(768), dim3(512), 0, stream>>>(q, k, v, nullptr, wb,
                                                 bq, bk, bv, Qp, Kp, VTp, nullptr);

  attn_kernel<<<dim3(1024), dim3(256), 0, stream>>>(Qp, Kp, VTp, cfg, ret);

  gemm3b<1><<<dim3(256), dim3(512), 0, stream>>>(nullptr, nullptr, nullptr, ret,
                                                 wb + 3 * WN, bo, nullptr, nullptr,
                                                 nullptr, nullptr, nullptr,
                                                 (float*)d_out);
}

// Round 8
// 191.587 us; speedup vs baseline: 1.0620x; 1.0620x over previous
//
#include <hip/hip_runtime.h>
#include <hip/hip_bf16.h>

// Fused MHA, B=8, S=1024, H=8, DK=128, D=1024, fp32 in/out, bf16 MFMA compute.
// convert -> QKV proj (256^2 8-phase counted-vmcnt GEMM, BAR-then-lgkm0 order,
// merged z=3, XCD swizzle, V^T epilogue) -> flash attn (swapped-QK in-lane
// softmax, cvt_pk, XCD swizzle, fused attn_arrange) -> out proj (128^2 2-phase,
// 512 blocks, XCD swizzle, fp32 out).

typedef __attribute__((ext_vector_type(8))) __bf16 bf16x8;
typedef __attribute__((ext_vector_type(4))) float f32x4;

#define DEV static __device__ __forceinline__

DEV float exp2v(float x) { return __builtin_amdgcn_exp2f(x); }

DEV unsigned short f2bf(float f) {
  union { float f; unsigned int u; } c; c.f = f;
  unsigned int u = c.u + 0x7fffu + ((c.u >> 16) & 1u);
  return (unsigned short)(u >> 16);
}

DEV unsigned cvtpk(float a, float b) {
  unsigned r;
  asm("v_cvt_pk_bf16_f32 %0, %1, %2" : "=v"(r) : "v"(a), "v"(b));
  return r;
}

DEV void gload16(const void* g, void* l) {
  __builtin_amdgcn_global_load_lds((const __attribute__((address_space(1))) void*)g,
                                   (__attribute__((address_space(3))) void*)l, 16, 0, 0);
}

// plain-loads feed the MFMAs, so the compiler tracks deps itself; this asm is
// the explicit phase gate only (no sched_barrier -- let the scheduler work).
#define LGKM0 asm volatile("s_waitcnt lgkmcnt(0)" ::: "memory")
#define BAR   __builtin_amdgcn_s_barrier()
#define VMC4  asm volatile("s_waitcnt vmcnt(4)" ::: "memory")
#define VMC0  asm volatile("s_waitcnt vmcnt(0)" ::: "memory")

// ---------------- convert: fp32->bf16 ----------------
DEV void cv4(const float* __restrict__ s, unsigned short* __restrict__ d, int i) {
  const float4 a = *(const float4*)(s + i);
  ushort4 o;
  o.x = f2bf(a.x); o.y = f2bf(a.y); o.z = f2bf(a.z); o.w = f2bf(a.w);
  *(ushort4*)(d + i) = o;
}

__global__ __launch_bounds__(256) void convert_kernel(
    const float* __restrict__ q, const float* __restrict__ k, const float* __restrict__ v,
    const float* __restrict__ wq, const float* __restrict__ wk,
    const float* __restrict__ wv, const float* __restrict__ wo,
    unsigned short* __restrict__ xq, unsigned short* __restrict__ xk,
    unsigned short* __restrict__ xv, unsigned short* __restrict__ wb)
{
  const int i = (blockIdx.x * 256 + threadIdx.x) * 4;
  cv4(q, xq, i);
  cv4(k, xk, i);
  cv4(v, xv, i);
  if (i < 4 * 1024 * 1024) {
    const int which = i >> 20, off = i & 1048575;
    const float* s = which == 0 ? wq : which == 1 ? wk : which == 2 ? wv : wo;
    cv4(s, wb + (which << 20), off);
  }
}

// ---------------- 256x256 8-phase GEMM (T2+T3+T4+T5), QKV merged ----------------
// C[m,n] = sum_k A[m,k] * Bt[n,k] + bias[n]. K=1024 (16 BK=64 tiles, 8 iters).
// 512 thr = 8 waves (2M x 4N), per-wave C = 128x64 (acc[8][4] f32x4).
// LDS 128 KiB: A[2buf][2half][128][128B] @0, B same @65536. XOR swizzle
// c ^= (r&7)<<4 on reads; stage uses linear LDS dest + inverse-swizzled
// global source. Counted vmcnt(4) gates at phases 4/8 only; raw s_barrier;
// template phase order: issue ds_reads+stage -> BAR -> lgkm0 -> MFMA -> BAR.
__global__ __launch_bounds__(512, 2) void gemm8p(
    const unsigned short* __restrict__ xq, const unsigned short* __restrict__ xk,
    const unsigned short* __restrict__ xv, const unsigned short* __restrict__ wb,
    const float* __restrict__ bq, const float* __restrict__ bk,
    const float* __restrict__ bv,
    unsigned short* __restrict__ Qp, unsigned short* __restrict__ Kp,
    unsigned short* __restrict__ VTp)
{
  __shared__ __align__(16) char LDS[131072];
  // 384 blocks = 8 XCD x 48
  const int swz = ((blockIdx.x & 7) * 48) + (blockIdx.x >> 3);
  const int z = swz >> 7; const int rem = swz & 127;
  const int mt = rem >> 2, nt = rem & 3;
  const int m0 = mt * 256, n0 = nt * 256;
  const unsigned short* Ag = z == 0 ? xq : z == 1 ? xk : xv;
  const unsigned short* Bg = wb + ((size_t)z << 20);
  const float* bias = z == 0 ? bq : z == 1 ? bk : bv;

  const int tid = threadIdx.x, lane = tid & 63, w = tid >> 6;
  const int wm = w >> 2, wn = w & 3;      // 2M x 4N wave grid
  const int g = lane >> 4, ln = lane & 15;

  const f32x4 fzero = {0.f, 0.f, 0.f, 0.f};
  f32x4 acc[8][4];
#pragma unroll
  for (int i = 0; i < 8; i++)
#pragma unroll
    for (int j = 0; j < 4; j++) acc[i][j] = fzero;

  bf16x8 bfr[4][2];   // B frags persist per K-tile
  bf16x8 afr[2][2];   // A mfrag-pair, transient per phase

  auto stageA = [&](int bf, int hf, int k0) {
    const unsigned short* src = Ag + (size_t)(m0 + hf * 128) * 1024 + k0;
    char* base = LDS + bf * 32768 + hf * 16384 + w * 2048;
#pragma unroll
    for (int r2 = 0; r2 < 2; ++r2) {
      const int o = w * 2048 + r2 * 1024 + lane * 16;
      const int rwi = o >> 7, cb = o & 127;
      gload16(src + (size_t)rwi * 1024 + ((cb ^ ((rwi & 7) << 4)) >> 1), base + r2 * 1024);
    }
  };
  auto stageB = [&](int bf, int hf, int k0) {
    const unsigned short* src = Bg + (size_t)(n0 + hf * 128) * 1024 + k0;
    char* base = LDS + 65536 + bf * 32768 + hf * 16384 + w * 2048;
#pragma unroll
    for (int r2 = 0; r2 < 2; ++r2) {
      const int o = w * 2048 + r2 * 1024 + lane * 16;
      const int rwi = o >> 7, cb = o & 127;
      gload16(src + (size_t)rwi * 1024 + ((cb ^ ((rwi & 7) << 4)) >> 1), base + r2 * 1024);
    }
  };
  auto rdA = [&](int bf, int q) {
#pragma unroll
    for (int p = 0; p < 2; ++p)
#pragma unroll
      for (int kc = 0; kc < 2; ++kc) {
        const int rwi = (2 * q + p) * 16 + ln;
        const int cb = (kc * 64 + g * 16) ^ ((rwi & 7) << 4);
        afr[p][kc] = *(const bf16x8*)(LDS + bf * 32768 + wm * 16384 + rwi * 128 + cb);
      }
  };
  auto rdB = [&](int bf) {
#pragma unroll
    for (int nf = 0; nf < 4; ++nf)
#pragma unroll
      for (int kc = 0; kc < 2; ++kc) {
        const int rwi = (wn & 1) * 64 + nf * 16 + ln;
        const int cb = (kc * 64 + g * 16) ^ ((rwi & 7) << 4);
        bfr[nf][kc] = *(const bf16x8*)(LDS + 65536 + bf * 32768 + (wn >> 1) * 16384 + rwi * 128 + cb);
      }
  };
  auto mm = [&](int q) {
    __builtin_amdgcn_s_setprio(1);
#pragma unroll
    for (int p = 0; p < 2; ++p)
#pragma unroll
      for (int nf = 0; nf < 4; ++nf)
#pragma unroll
        for (int kc = 0; kc < 2; ++kc)
          acc[2 * q + p][nf] =
              __builtin_amdgcn_mfma_f32_16x16x32_bf16(afr[p][kc], bfr[nf][kc],
                                                      acc[2 * q + p][nf], 0, 0, 0);
    __builtin_amdgcn_s_setprio(0);
  };

  // prologue: t0 {B0,B1,A0,A1} + t1 {B0,B1}; gate keeps t1:B in flight
  stageB(0, 0, 0); stageB(0, 1, 0);
  stageA(0, 0, 0); stageA(0, 1, 0);
  stageB(1, 0, 64); stageB(1, 1, 64);
  VMC4; BAR;

  for (int j = 0; j < 8; ++j) {
    const int kO = (2 * j + 1) << 6, kNE = (2 * j + 2) << 6, kNO = (2 * j + 3) << 6;
    const bool pf = j < 7;
    // ph1: even tile (buf0) q0; stage odd:A0
    rdB(0); rdA(0, 0); stageA(1, 0, kO);
    BAR; LGKM0; mm(0); BAR;
    // ph2: q1; stage odd:A1
    rdA(0, 1); stageA(1, 1, kO);
    BAR; LGKM0; mm(1); BAR;
    // ph3: q2; stage t+2:B0
    rdA(0, 2); if (pf) stageB(0, 0, kNE);
    BAR; LGKM0; mm(2); BAR;
    // ph4: q3; stage t+2:B1; GATE for odd tile
    rdA(0, 3); if (pf) stageB(0, 1, kNE);
    BAR; LGKM0; mm(3);
    if (pf) { VMC4; } else { VMC0; }
    BAR;
    // ph5: odd tile (buf1) q0; stage t+2:A0
    rdB(1); rdA(1, 0); if (pf) stageA(0, 0, kNE);
    BAR; LGKM0; mm(0); BAR;
    // ph6: q1; stage t+2:A1
    rdA(1, 1); if (pf) stageA(0, 1, kNE);
    BAR; LGKM0; mm(1); BAR;
    // ph7: q2; stage t+3:B0
    rdA(1, 2); if (pf) stageB(1, 0, kNO);
    BAR; LGKM0; mm(2); BAR;
    // ph8: q3; stage t+3:B1; GATE for t+2
    rdA(1, 3); if (pf) stageB(1, 1, kNO);
    BAR; LGKM0; mm(3);
    if (pf) { VMC4; }
    BAR;
  }

  // epilogue
  const float QS = 0.12751743f;   // 1/sqrt(128)*log2(e)
#pragma unroll
  for (int mf = 0; mf < 8; ++mf)
#pragma unroll
    for (int nf = 0; nf < 4; ++nf) {
      const int m = m0 + wm * 128 + mf * 16 + g * 4;
      const int n = n0 + wn * 64 + nf * 16 + ln;
      const float bn = bias[n];
      if (z == 0) {
#pragma unroll
        for (int r = 0; r < 4; ++r)
          Qp[(size_t)(m + r) * 1024 + n] = f2bf((acc[mf][nf][r] + bn) * QS);
      } else if (z == 1) {
#pragma unroll
        for (int r = 0; r < 4; ++r)
          Kp[(size_t)(m + r) * 1024 + n] = f2bf(acc[mf][nf][r] + bn);
      } else {
        const int b = m >> 10, s0 = m & 1023;   // n = h*128+dk
        uint2 pk;
        pk.x = cvtpk(acc[mf][nf][0] + bn, acc[mf][nf][1] + bn);
        pk.y = cvtpk(acc[mf][nf][2] + bn, acc[mf][nf][3] + bn);
        *(uint2*)(VTp + (((size_t)(b * 8) << 7 | n) << 10) + s0) = pk;
      }
    }
}

// ---------------- out projection GEMM: 128^2 single-buf 2-phase, fp32 out ----------------
// 512 blocks (8 XCD x 64), 256 thr (4 waves 2x2), known-good round-4 structure.
__global__ __launch_bounds__(256) void gemm_out(
    const unsigned short* __restrict__ A, const unsigned short* __restrict__ Bt,
    const float* __restrict__ bias, float* __restrict__ Cout)
{
  __shared__ __align__(16) unsigned short As[128 * 64];
  __shared__ __align__(16) unsigned short Bs[128 * 64];
  const int bid = blockIdx.x;
  const int swz = (bid & 7) * 64 + (bid >> 3);     // 512 = 8 x 64
  const int m0 = (swz >> 3) * 128, n0 = (swz & 7) * 128;
  const int tid = threadIdx.x;
  const int lane = tid & 63, w = tid >> 6;
  const int wr = w >> 1, wc = w & 1;
  const int g = lane >> 4, ln = lane & 15;
  const f32x4 fzero = {0.f, 0.f, 0.f, 0.f};

  f32x4 acc[4][4];
#pragma unroll
  for (int i = 0; i < 4; i++)
#pragma unroll
    for (int j = 0; j < 4; j++) acc[i][j] = fzero;

  for (int k0 = 0; k0 < 1024; k0 += 64) {
    __syncthreads();
#pragma unroll
    for (int i = 0; i < 4; ++i) {
      const int obase = i * 4096 + w * 1024;
      const int o = obase + lane * 16;
      const int r = o >> 7, cb = o & 127;
      gload16(A  + (size_t)(m0 + r) * 1024 + k0 + (cb >> 1), (char*)As + obase);
      gload16(Bt + (size_t)(n0 + r) * 1024 + k0 + (cb >> 1), (char*)Bs + obase);
    }
    asm volatile("s_waitcnt vmcnt(0)" ::: "memory");
    __syncthreads();
#pragma unroll
    for (int kc = 0; kc < 2; ++kc) {
      const int ko = kc * 32 + g * 8;
      bf16x8 af[4], bfr[4];
#pragma unroll
      for (int mi = 0; mi < 4; ++mi)
        af[mi] = *(const bf16x8*)(As + (wr * 64 + mi * 16 + ln) * 64 + ko);
#pragma unroll
      for (int ni = 0; ni < 4; ++ni)
        bfr[ni] = *(const bf16x8*)(Bs + (wc * 64 + ni * 16 + ln) * 64 + ko);
#pragma unroll
      for (int mi = 0; mi < 4; ++mi)
#pragma unroll
        for (int ni = 0; ni < 4; ++ni)
          acc[mi][ni] = __builtin_amdgcn_mfma_f32_16x16x32_bf16(af[mi], bfr[ni], acc[mi][ni], 0, 0, 0);
    }
  }

#pragma unroll
  for (int mi = 0; mi < 4; ++mi)
#pragma unroll
    for (int ni = 0; ni < 4; ++ni) {
      const int mb = m0 + wr * 64 + mi * 16 + g * 4;
      const int n  = n0 + wc * 64 + ni * 16 + ln;
      const float bn = bias[n];
#pragma unroll
      for (int r = 0; r < 4; ++r)
        Cout[(size_t)(mb + r) * 1024 + n] = acc[mi][ni][r] + bn;
    }
}

// ---------------- flash attention + fused attn_arrange (+zero pad) ----------------
__global__ __launch_bounds__(256) void attn_kernel(
    const unsigned short* __restrict__ Qp, const unsigned short* __restrict__ Kp,
    const unsigned short* __restrict__ VT, const int* __restrict__ cfg,
    unsigned short* __restrict__ ret)
{
  __shared__ __align__(16) unsigned short Ks[2][64 * 128];
  __shared__ __align__(16) unsigned short Vs[2][128 * 64];
  __shared__ __align__(16) unsigned short Ps[4 * 16 * 64];
  const int bx = blockIdx.x;
  const int qb = bx >> 6, bh = bx & 63, b = bh >> 3, h = bh & 7;
  const int tid = threadIdx.x, lane = tid & 63, w = tid >> 6;
  const int g = lane >> 4, ln = lane & 15;
  const int q0 = qb * 64;
  const f32x4 fzero = {0.f, 0.f, 0.f, 0.f};

  bf16x8 qf[4];
  {
    const unsigned short* qrow = Qp + ((size_t)(b * 1024 + q0 + w * 16 + ln)) * 1024 + h * 128;
#pragma unroll
    for (int kc = 0; kc < 4; kc++) qf[kc] = *(const bf16x8*)(qrow + kc * 32 + g * 8);
  }
  float m_run = -1e30f, l_run = 0.f;
  f32x4 o_acc[8];
#pragma unroll
  for (int i = 0; i < 8; i++) o_acc[i] = fzero;

  auto stage = [&](int buf, int kv0) {
#pragma unroll
    for (int i = 0; i < 4; ++i) {
      const int obase = i * 4096 + w * 1024;
      const int o = obase + lane * 16;
      {
        const int r = o >> 8, cb = o & 255;
        const int cs = cb ^ ((r & 7) << 4);
        gload16(Kp + ((size_t)(b * 1024 + kv0 + r)) * 1024 + h * 128 + (cs >> 1),
                (char*)Ks + buf * 16384 + obase);
      }
      {
        const int r = o >> 7, cb = o & 127;
        const int cs = cb ^ ((r & 7) << 4);
        gload16(VT + ((size_t)((b * 8 + h) * 128 + r)) * 1024 + kv0 + (cs >> 1),
                (char*)Vs + buf * 16384 + obase);
      }
    }
  };

  stage(0, 0);
  asm volatile("s_waitcnt vmcnt(0)" ::: "memory");
  __syncthreads();

  int cur = 0;
  for (int t = 0; t < 16; ++t) {
    if (t < 15) stage(cur ^ 1, (t + 1) * 64);

    f32x4 sc[4];
    __builtin_amdgcn_s_setprio(1);
#pragma unroll
    for (int nb = 0; nb < 4; ++nb) {
      sc[nb] = fzero;
      const int rr = nb * 16 + ln;
      const int sw = (rr & 7) << 4;
#pragma unroll
      for (int kc = 0; kc < 4; ++kc) {
        const bf16x8 kf = *(const bf16x8*)((const char*)Ks + cur * 16384 + rr * 256 +
                                           (((kc * 32 + g * 8) << 1) ^ sw));
        sc[nb] = __builtin_amdgcn_mfma_f32_16x16x32_bf16(kf, qf[kc], sc[nb], 0, 0, 0);
      }
    }
    __builtin_amdgcn_s_setprio(0);

    float mnb[4];
#pragma unroll
    for (int nb = 0; nb < 4; ++nb)
      mnb[nb] = fmaxf(fmaxf(sc[nb][0], sc[nb][1]), fmaxf(sc[nb][2], sc[nb][3]));
    float pmax = fmaxf(fmaxf(mnb[0], mnb[1]), fmaxf(mnb[2], mnb[3]));
    pmax = fmaxf(pmax, __shfl_xor(pmax, 16));
    pmax = fmaxf(pmax, __shfl_xor(pmax, 32));
    if (__any(pmax > m_run + 11.5f)) {
      const float mnew = fmaxf(m_run, pmax);
      const float alpha = exp2v(m_run - mnew);
      l_run *= alpha;
      m_run = mnew;
      float ar[4];
#pragma unroll
      for (int r = 0; r < 4; ++r)
        ar[r] = __shfl(alpha, (lane & 48) | (((lane >> 4) & 3) << 2) | r);
#pragma unroll
      for (int i = 0; i < 8; i++)
#pragma unroll
        for (int r = 0; r < 4; r++) o_acc[i][r] *= ar[r];
    }
    float sum = 0.f;
    float pvv[16];
#pragma unroll
    for (int nb = 0; nb < 4; ++nb)
#pragma unroll
      for (int r = 0; r < 4; ++r) {
        const float p = exp2v(sc[nb][r] - m_run);
        pvv[nb * 4 + r] = p; sum += p;
      }
    l_run += sum;

    {
      char* pbase = (char*)Ps + w * 2048 + ln * 128;
#pragma unroll
      for (int nb = 0; nb < 4; ++nb) {
        uint2 pk;
        pk.x = cvtpk(pvv[nb * 4 + 0], pvv[nb * 4 + 1]);
        pk.y = cvtpk(pvv[nb * 4 + 2], pvv[nb * 4 + 3]);
        *(uint2*)(pbase + (((16 * nb + 4 * g) << 1) ^ ((ln & 7) << 4))) = pk;
      }
    }
    bf16x8 pf[2];
#pragma unroll
    for (int kc = 0; kc < 2; kc++)
      pf[kc] = *(const bf16x8*)((const char*)Ps + w * 2048 + ln * 128 +
                                (((kc * 32 + g * 8) << 1) ^ ((ln & 7) << 4)));

    __builtin_amdgcn_s_setprio(1);
#pragma unroll
    for (int nb2 = 0; nb2 < 8; ++nb2) {
      const int rr = nb2 * 16 + ln;
      const int sw = (rr & 7) << 4;
#pragma unroll
      for (int kc = 0; kc < 2; ++kc) {
        const bf16x8 vf = *(const bf16x8*)((const char*)Vs + cur * 16384 + rr * 128 +
                                           (((kc * 32 + g * 8) << 1) ^ sw));
        o_acc[nb2] = __builtin_amdgcn_mfma_f32_16x16x32_bf16(pf[kc], vf, o_acc[nb2], 0, 0, 0);
      }
    }
    __builtin_amdgcn_s_setprio(0);

    if (t < 15) {
      asm volatile("s_waitcnt vmcnt(0)" ::: "memory");
      __syncthreads();
    }
    cur ^= 1;
  }

  l_run += __shfl_xor(l_run, 16);
  l_run += __shfl_xor(l_run, 32);
  float rl[4];
#pragma unroll
  for (int r = 0; r < 4; ++r)
    rl[r] = 1.0f / __shfl(l_run, (lane & 48) | (((lane >> 4) & 3) << 2) | r);
  const int d_b = 32 * (cfg[b] + 1);
  const int zw = 128 - d_b;
  const size_t rowbase = (size_t)(b * 1024 + q0 + w * 16 + g * 4);
#pragma unroll
  for (int nb2 = 0; nb2 < 8; ++nb2) {
    const int dk = nb2 * 16 + ln;
    if (dk < d_b) {
#pragma unroll
      for (int r = 0; r < 4; r++)
        ret[(rowbase + r) * 1024 + h * d_b + dk] = f2bf(o_acc[nb2][r] * rl[r]);
    } else {
#pragma unroll
      for (int r = 0; r < 4; r++)
        ret[(rowbase + r) * 1024 + 8 * d_b + h * zw + (dk - d_b)] = 0;
    }
  }
}

// ---------------- launch ----------------
extern "C" void kernel_launch(void* const* d_in, const int* in_sizes, int n_in,
                              void* d_out, int out_size, void* d_ws, size_t ws_size,
                              hipStream_t stream)
{
  (void)in_sizes; (void)n_in; (void)out_size; (void)ws_size;
  const float* q   = (const float*)d_in[0];
  const float* k   = (const float*)d_in[1];
  const float* v   = (const float*)d_in[2];
  const int*   cfg = (const int*)d_in[3];
  const float* Wq  = (const float*)d_in[4];  const float* bq = (const float*)d_in[5];
  const float* Wk  = (const float*)d_in[6];  const float* bk = (const float*)d_in[7];
  const float* Wv  = (const float*)d_in[8];  const float* bv = (const float*)d_in[9];
  const float* Wo  = (const float*)d_in[10]; const float* bo = (const float*)d_in[11];

  const size_t X  = 8192ull * 1024ull;
  const size_t WN = 1024ull * 1024ull;
  char* p = (char*)d_ws;
  unsigned short* xq  = (unsigned short*)p; p += X * 2;
  unsigned short* xk  = (unsigned short*)p; p += X * 2;
  unsigned short* xv  = (unsigned short*)p; p += X * 2;
  unsigned short* wb  = (unsigned short*)p; p += 4 * WN * 2;
  unsigned short* Qp  = (unsigned short*)p; p += X * 2;
  unsigned short* Kp  = (unsigned short*)p; p += X * 2;
  unsigned short* VTp = (unsigned short*)p; p += X * 2;
  unsigned short* ret = (unsigned short*)p; p += X * 2;

  convert_kernel<<<dim3(8192), dim3(256), 0, stream>>>(q, k, v, Wq, Wk, Wv, Wo,
                                                       xq, xk, xv, wb);

  gemm8p<<<dim3(384), dim3(512), 0, stream>>>(xq, xk, xv, wb, bq, bk, bv,
                                              Qp, Kp, VTp);

  attn_kernel<<<dim3(1024), dim3(256), 0, stream>>>(Qp, Kp, VTp, cfg, ret);

  gemm_out<<<dim3(512), dim3(256), 0, stream>>>(ret, wb + 3 * WN, bo, (float*)d_out);
}

// Round 9
// 176.674 us; speedup vs baseline: 1.1517x; 1.0844x over previous
//
#include <hip/hip_runtime.h>
#include <hip/hip_bf16.h>

// Fused MHA, B=8, S=1024, H=8, DK=128, D=1024, fp32 in/out, bf16 MFMA compute.
// convert -> QKV proj (256^2 8-phase counted-vmcnt GEMM, merged z=3, XCD swizzle,
// V^T epilogue) -> flash attn (QBLK=128, 8 waves, swapped-QK in-lane softmax,
// cvt_pk, XCD swizzle, fused attn_arrange) -> out proj (128^2 2-phase, 512 blocks).

typedef __attribute__((ext_vector_type(8))) __bf16 bf16x8;
typedef __attribute__((ext_vector_type(4))) float f32x4;

#define DEV static __device__ __forceinline__

DEV float exp2v(float x) { return __builtin_amdgcn_exp2f(x); }

DEV unsigned short f2bf(float f) {
  union { float f; unsigned int u; } c; c.f = f;
  unsigned int u = c.u + 0x7fffu + ((c.u >> 16) & 1u);
  return (unsigned short)(u >> 16);
}

DEV unsigned cvtpk(float a, float b) {
  unsigned r;
  asm("v_cvt_pk_bf16_f32 %0, %1, %2" : "=v"(r) : "v"(a), "v"(b));
  return r;
}

DEV void gload16(const void* g, void* l) {
  __builtin_amdgcn_global_load_lds((const __attribute__((address_space(1))) void*)g,
                                   (__attribute__((address_space(3))) void*)l, 16, 0, 0);
}

#define LGKM0 asm volatile("s_waitcnt lgkmcnt(0)" ::: "memory")
#define BAR   __builtin_amdgcn_s_barrier()
#define VMC4  asm volatile("s_waitcnt vmcnt(4)" ::: "memory")
#define VMC0  asm volatile("s_waitcnt vmcnt(0)" ::: "memory")

// ---------------- convert: fp32->bf16 ----------------
DEV void cv4(const float* __restrict__ s, unsigned short* __restrict__ d, int i) {
  const float4 a = *(const float4*)(s + i);
  ushort4 o;
  o.x = f2bf(a.x); o.y = f2bf(a.y); o.z = f2bf(a.z); o.w = f2bf(a.w);
  *(ushort4*)(d + i) = o;
}

__global__ __launch_bounds__(256) void convert_kernel(
    const float* __restrict__ q, const float* __restrict__ k, const float* __restrict__ v,
    const float* __restrict__ wq, const float* __restrict__ wk,
    const float* __restrict__ wv, const float* __restrict__ wo,
    unsigned short* __restrict__ xq, unsigned short* __restrict__ xk,
    unsigned short* __restrict__ xv, unsigned short* __restrict__ wb)
{
  const int i = (blockIdx.x * 256 + threadIdx.x) * 4;
  cv4(q, xq, i);
  cv4(k, xk, i);
  cv4(v, xv, i);
  if (i < 4 * 1024 * 1024) {
    const int which = i >> 20, off = i & 1048575;
    const float* s = which == 0 ? wq : which == 1 ? wk : which == 2 ? wv : wo;
    cv4(s, wb + (which << 20), off);
  }
}

// ---------------- 256x256 8-phase GEMM (T2+T3+T4+T5), QKV merged ----------------
__global__ __launch_bounds__(512, 2) void gemm8p(
    const unsigned short* __restrict__ xq, const unsigned short* __restrict__ xk,
    const unsigned short* __restrict__ xv, const unsigned short* __restrict__ wb,
    const float* __restrict__ bq, const float* __restrict__ bk,
    const float* __restrict__ bv,
    unsigned short* __restrict__ Qp, unsigned short* __restrict__ Kp,
    unsigned short* __restrict__ VTp)
{
  __shared__ __align__(16) char LDS[131072];
  // 384 blocks = 8 XCD x 48
  const int swz = ((blockIdx.x & 7) * 48) + (blockIdx.x >> 3);
  const int z = swz >> 7; const int rem = swz & 127;
  const int mt = rem >> 2, nt = rem & 3;
  const int m0 = mt * 256, n0 = nt * 256;
  const unsigned short* Ag = z == 0 ? xq : z == 1 ? xk : xv;
  const unsigned short* Bg = wb + ((size_t)z << 20);
  const float* bias = z == 0 ? bq : z == 1 ? bk : bv;

  const int tid = threadIdx.x, lane = tid & 63, w = tid >> 6;
  const int wm = w >> 2, wn = w & 3;      // 2M x 4N wave grid
  const int g = lane >> 4, ln = lane & 15;

  const f32x4 fzero = {0.f, 0.f, 0.f, 0.f};
  f32x4 acc[8][4];
#pragma unroll
  for (int i = 0; i < 8; i++)
#pragma unroll
    for (int j = 0; j < 4; j++) acc[i][j] = fzero;

  bf16x8 bfr[4][2];   // B frags persist per K-tile
  bf16x8 afr[2][2];   // A mfrag-pair, transient per phase

  auto stageA = [&](int bf, int hf, int k0) {
    const unsigned short* src = Ag + (size_t)(m0 + hf * 128) * 1024 + k0;
    char* base = LDS + bf * 32768 + hf * 16384 + w * 2048;
#pragma unroll
    for (int r2 = 0; r2 < 2; ++r2) {
      const int o = w * 2048 + r2 * 1024 + lane * 16;
      const int rwi = o >> 7, cb = o & 127;
      gload16(src + (size_t)rwi * 1024 + ((cb ^ ((rwi & 7) << 4)) >> 1), base + r2 * 1024);
    }
  };
  auto stageB = [&](int bf, int hf, int k0) {
    const unsigned short* src = Bg + (size_t)(n0 + hf * 128) * 1024 + k0;
    char* base = LDS + 65536 + bf * 32768 + hf * 16384 + w * 2048;
#pragma unroll
    for (int r2 = 0; r2 < 2; ++r2) {
      const int o = w * 2048 + r2 * 1024 + lane * 16;
      const int rwi = o >> 7, cb = o & 127;
      gload16(src + (size_t)rwi * 1024 + ((cb ^ ((rwi & 7) << 4)) >> 1), base + r2 * 1024);
    }
  };
  auto rdA = [&](int bf, int q) {
#pragma unroll
    for (int p = 0; p < 2; ++p)
#pragma unroll
      for (int kc = 0; kc < 2; ++kc) {
        const int rwi = (2 * q + p) * 16 + ln;
        const int cb = (kc * 64 + g * 16) ^ ((rwi & 7) << 4);
        afr[p][kc] = *(const bf16x8*)(LDS + bf * 32768 + wm * 16384 + rwi * 128 + cb);
      }
  };
  auto rdB = [&](int bf) {
#pragma unroll
    for (int nf = 0; nf < 4; ++nf)
#pragma unroll
      for (int kc = 0; kc < 2; ++kc) {
        const int rwi = (wn & 1) * 64 + nf * 16 + ln;
        const int cb = (kc * 64 + g * 16) ^ ((rwi & 7) << 4);
        bfr[nf][kc] = *(const bf16x8*)(LDS + 65536 + bf * 32768 + (wn >> 1) * 16384 + rwi * 128 + cb);
      }
  };
  auto mm = [&](int q) {
    __builtin_amdgcn_s_setprio(1);
#pragma unroll
    for (int p = 0; p < 2; ++p)
#pragma unroll
      for (int nf = 0; nf < 4; ++nf)
#pragma unroll
        for (int kc = 0; kc < 2; ++kc)
          acc[2 * q + p][nf] =
              __builtin_amdgcn_mfma_f32_16x16x32_bf16(afr[p][kc], bfr[nf][kc],
                                                      acc[2 * q + p][nf], 0, 0, 0);
    __builtin_amdgcn_s_setprio(0);
  };

  // prologue: t0 {B0,B1,A0,A1} + t1 {B0,B1}; gate keeps t1:B in flight
  stageB(0, 0, 0); stageB(0, 1, 0);
  stageA(0, 0, 0); stageA(0, 1, 0);
  stageB(1, 0, 64); stageB(1, 1, 64);
  VMC4; BAR;

  for (int j = 0; j < 8; ++j) {
    const int kO = (2 * j + 1) << 6, kNE = (2 * j + 2) << 6, kNO = (2 * j + 3) << 6;
    const bool pf = j < 7;
    // ph1: even tile (buf0) q0; stage odd:A0
    rdB(0); rdA(0, 0); stageA(1, 0, kO);
    BAR; LGKM0; mm(0); BAR;
    // ph2: q1; stage odd:A1
    rdA(0, 1); stageA(1, 1, kO);
    BAR; LGKM0; mm(1); BAR;
    // ph3: q2; stage t+2:B0
    rdA(0, 2); if (pf) stageB(0, 0, kNE);
    BAR; LGKM0; mm(2); BAR;
    // ph4: q3; stage t+2:B1; GATE for odd tile
    rdA(0, 3); if (pf) stageB(0, 1, kNE);
    BAR; LGKM0; mm(3);
    if (pf) { VMC4; } else { VMC0; }
    BAR;
    // ph5: odd tile (buf1) q0; stage t+2:A0
    rdB(1); rdA(1, 0); if (pf) stageA(0, 0, kNE);
    BAR; LGKM0; mm(0); BAR;
    // ph6: q1; stage t+2:A1
    rdA(1, 1); if (pf) stageA(0, 1, kNE);
    BAR; LGKM0; mm(1); BAR;
    // ph7: q2; stage t+3:B0
    rdA(1, 2); if (pf) stageB(1, 0, kNO);
    BAR; LGKM0; mm(2); BAR;
    // ph8: q3; stage t+3:B1; GATE for t+2
    rdA(1, 3); if (pf) stageB(1, 1, kNO);
    BAR; LGKM0; mm(3);
    if (pf) { VMC4; }
    BAR;
  }

  // epilogue
  const float QS = 0.12751743f;   // 1/sqrt(128)*log2(e)
#pragma unroll
  for (int mf = 0; mf < 8; ++mf)
#pragma unroll
    for (int nf = 0; nf < 4; ++nf) {
      const int m = m0 + wm * 128 + mf * 16 + g * 4;
      const int n = n0 + wn * 64 + nf * 16 + ln;
      const float bn = bias[n];
      if (z == 0) {
#pragma unroll
        for (int r = 0; r < 4; ++r)
          Qp[(size_t)(m + r) * 1024 + n] = f2bf((acc[mf][nf][r] + bn) * QS);
      } else if (z == 1) {
#pragma unroll
        for (int r = 0; r < 4; ++r)
          Kp[(size_t)(m + r) * 1024 + n] = f2bf(acc[mf][nf][r] + bn);
      } else {
        const int b = m >> 10, s0 = m & 1023;   // n = h*128+dk
        uint2 pk;
        pk.x = cvtpk(acc[mf][nf][0] + bn, acc[mf][nf][1] + bn);
        pk.y = cvtpk(acc[mf][nf][2] + bn, acc[mf][nf][3] + bn);
        *(uint2*)(VTp + (((size_t)(b * 8) << 7 | n) << 10) + s0) = pk;
      }
    }
}

// ---------------- out projection GEMM: 128^2 single-buf 2-phase, fp32 out ----------------
__global__ __launch_bounds__(256) void gemm_out(
    const unsigned short* __restrict__ A, const unsigned short* __restrict__ Bt,
    const float* __restrict__ bias, float* __restrict__ Cout)
{
  __shared__ __align__(16) unsigned short As[128 * 64];
  __shared__ __align__(16) unsigned short Bs[128 * 64];
  const int bid = blockIdx.x;
  const int swz = (bid & 7) * 64 + (bid >> 3);     // 512 = 8 x 64
  const int m0 = (swz >> 3) * 128, n0 = (swz & 7) * 128;
  const int tid = threadIdx.x;
  const int lane = tid & 63, w = tid >> 6;
  const int wr = w >> 1, wc = w & 1;
  const int g = lane >> 4, ln = lane & 15;
  const f32x4 fzero = {0.f, 0.f, 0.f, 0.f};

  f32x4 acc[4][4];
#pragma unroll
  for (int i = 0; i < 4; i++)
#pragma unroll
    for (int j = 0; j < 4; j++) acc[i][j] = fzero;

  for (int k0 = 0; k0 < 1024; k0 += 64) {
    __syncthreads();
#pragma unroll
    for (int i = 0; i < 4; ++i) {
      const int obase = i * 4096 + w * 1024;
      const int o = obase + lane * 16;
      const int r = o >> 7, cb = o & 127;
      gload16(A  + (size_t)(m0 + r) * 1024 + k0 + (cb >> 1), (char*)As + obase);
      gload16(Bt + (size_t)(n0 + r) * 1024 + k0 + (cb >> 1), (char*)Bs + obase);
    }
    asm volatile("s_waitcnt vmcnt(0)" ::: "memory");
    __syncthreads();
#pragma unroll
    for (int kc = 0; kc < 2; ++kc) {
      const int ko = kc * 32 + g * 8;
      bf16x8 af[4], bfr[4];
#pragma unroll
      for (int mi = 0; mi < 4; ++mi)
        af[mi] = *(const bf16x8*)(As + (wr * 64 + mi * 16 + ln) * 64 + ko);
#pragma unroll
      for (int ni = 0; ni < 4; ++ni)
        bfr[ni] = *(const bf16x8*)(Bs + (wc * 64 + ni * 16 + ln) * 64 + ko);
#pragma unroll
      for (int mi = 0; mi < 4; ++mi)
#pragma unroll
        for (int ni = 0; ni < 4; ++ni)
          acc[mi][ni] = __builtin_amdgcn_mfma_f32_16x16x32_bf16(af[mi], bfr[ni], acc[mi][ni], 0, 0, 0);
    }
  }

#pragma unroll
  for (int mi = 0; mi < 4; ++mi)
#pragma unroll
    for (int ni = 0; ni < 4; ++ni) {
      const int mb = m0 + wr * 64 + mi * 16 + g * 4;
      const int n  = n0 + wc * 64 + ni * 16 + ln;
      const float bn = bias[n];
#pragma unroll
      for (int r = 0; r < 4; ++r)
        Cout[(size_t)(mb + r) * 1024 + n] = acc[mi][ni][r] + bn;
    }
}

// ---------------- flash attention + fused attn_arrange (+zero pad) ----------------
// Grid 512 = 8 qb x 64 (b,h); XCD-coherent (qb*64 ≡ 0 mod 8 -> all q-blocks of a
// (b,h) on one XCD). 512 thr = 8 waves x 16 q-rows = QBLK 128. KV chunks of 64
// double-buffered, staged once per chunk for 128 q-rows (2x amortization vs r8).
__global__ __launch_bounds__(512) void attn_kernel(
    const unsigned short* __restrict__ Qp, const unsigned short* __restrict__ Kp,
    const unsigned short* __restrict__ VT, const int* __restrict__ cfg,
    unsigned short* __restrict__ ret)
{
  __shared__ __align__(16) unsigned short Ks[2][64 * 128];
  __shared__ __align__(16) unsigned short Vs[2][128 * 64];
  __shared__ __align__(16) unsigned short Ps[8 * 16 * 64];
  const int bx = blockIdx.x;
  const int qb = bx >> 6, bh = bx & 63, b = bh >> 3, h = bh & 7;
  const int tid = threadIdx.x, lane = tid & 63, w = tid >> 6;
  const int g = lane >> 4, ln = lane & 15;
  const int q0 = qb * 128;
  const f32x4 fzero = {0.f, 0.f, 0.f, 0.f};

  // Q fragments: B-operand layout (col=q=ln, k-slice = kc*32+g*8). Pre-scaled.
  bf16x8 qf[4];
  {
    const unsigned short* qrow = Qp + ((size_t)(b * 1024 + q0 + w * 16 + ln)) * 1024 + h * 128;
#pragma unroll
    for (int kc = 0; kc < 4; kc++) qf[kc] = *(const bf16x8*)(qrow + kc * 32 + g * 8);
  }
  float m_run = -1e30f, l_run = 0.f;
  f32x4 o_acc[8];
#pragma unroll
  for (int i = 0; i < 8; i++) o_acc[i] = fzero;

  // stage one KV chunk: 512 thr, K 16KB (2 units), V 16KB (2 units)
  auto stage = [&](int buf, int kv0) {
#pragma unroll
    for (int i = 0; i < 2; ++i) {
      const int o = i * 8192 + tid * 16;
      {  // K chunk rows kv (256B/row), pre-swizzled source
        const int r = o >> 8, cb = o & 255;
        const int cs = cb ^ ((r & 7) << 4);
        gload16(Kp + ((size_t)(b * 1024 + kv0 + r)) * 1024 + h * 128 + (cs >> 1),
                (char*)Ks + buf * 16384 + o);
      }
      {  // V^T chunk rows dk (128B/row), pre-swizzled source
        const int r = o >> 7, cb = o & 127;
        const int cs = cb ^ ((r & 7) << 4);
        gload16(VT + ((size_t)((b * 8 + h) * 128 + r)) * 1024 + kv0 + (cs >> 1),
                (char*)Vs + buf * 16384 + o);
      }
    }
  };

  stage(0, 0);
  asm volatile("s_waitcnt vmcnt(0)" ::: "memory");
  __syncthreads();

  int cur = 0;
  for (int t = 0; t < 16; ++t) {
    if (t < 15) stage(cur ^ 1, (t + 1) * 64);   // issue-early prefetch

    // QK^T swapped: sc = S^T tile. Lane holds q=ln, kv = 16*nb + 4*g + r.
    f32x4 sc[4];
    __builtin_amdgcn_s_setprio(1);
#pragma unroll
    for (int nb = 0; nb < 4; ++nb) {
      sc[nb] = fzero;
      const int rr = nb * 16 + ln;
      const int sw = (rr & 7) << 4;
#pragma unroll
      for (int kc = 0; kc < 4; ++kc) {
        const bf16x8 kf = *(const bf16x8*)((const char*)Ks + cur * 16384 + rr * 256 +
                                           (((kc * 32 + g * 8) << 1) ^ sw));
        sc[nb] = __builtin_amdgcn_mfma_f32_16x16x32_bf16(kf, qf[kc], sc[nb], 0, 0, 0);
      }
    }
    __builtin_amdgcn_s_setprio(0);

    // in-lane online softmax (log2 domain), tree max
    float mnb[4];
#pragma unroll
    for (int nb = 0; nb < 4; ++nb)
      mnb[nb] = fmaxf(fmaxf(sc[nb][0], sc[nb][1]), fmaxf(sc[nb][2], sc[nb][3]));
    float pmax = fmaxf(fmaxf(mnb[0], mnb[1]), fmaxf(mnb[2], mnb[3]));
    pmax = fmaxf(pmax, __shfl_xor(pmax, 16));
    pmax = fmaxf(pmax, __shfl_xor(pmax, 32));
    if (__any(pmax > m_run + 11.5f)) {       // defer-max: rare after chunk 0
      const float mnew = fmaxf(m_run, pmax);
      const float alpha = exp2v(m_run - mnew);
      l_run *= alpha;
      m_run = mnew;
      float ar[4];
#pragma unroll
      for (int r = 0; r < 4; ++r)
        ar[r] = __shfl(alpha, (lane & 48) | (((lane >> 4) & 3) << 2) | r);
#pragma unroll
      for (int i = 0; i < 8; i++)
#pragma unroll
        for (int r = 0; r < 4; r++) o_acc[i][r] *= ar[r];
    }
    float sum = 0.f;
    float pvv[16];
#pragma unroll
    for (int nb = 0; nb < 4; ++nb)
#pragma unroll
      for (int r = 0; r < 4; ++r) {
        const float p = exp2v(sc[nb][r] - m_run);
        pvv[nb * 4 + r] = p; sum += p;
      }
    l_run += sum;   // in-lane partial; cross-lane reduce deferred to epilogue

    // P -> per-wave LDS via cvt_pk: row q=ln (128B), byte = 2*kv ^ ((ln&7)<<4)
    {
      char* pbase = (char*)Ps + w * 2048 + ln * 128;
#pragma unroll
      for (int nb = 0; nb < 4; ++nb) {
        uint2 pk;
        pk.x = cvtpk(pvv[nb * 4 + 0], pvv[nb * 4 + 1]);
        pk.y = cvtpk(pvv[nb * 4 + 2], pvv[nb * 4 + 3]);
        *(uint2*)(pbase + (((16 * nb + 4 * g) << 1) ^ ((ln & 7) << 4))) = pk;
      }
    }
    bf16x8 pf[2];
#pragma unroll
    for (int kc = 0; kc < 2; kc++)
      pf[kc] = *(const bf16x8*)((const char*)Ps + w * 2048 + ln * 128 +
                                (((kc * 32 + g * 8) << 1) ^ ((ln & 7) << 4)));

    // PV: o_acc[nb2] over dk block nb2; lane holds dk=ln+16*nb2, q rows 4g+r
    __builtin_amdgcn_s_setprio(1);
#pragma unroll
    for (int nb2 = 0; nb2 < 8; ++nb2) {
      const int rr = nb2 * 16 + ln;
      const int sw = (rr & 7) << 4;
#pragma unroll
      for (int kc = 0; kc < 2; ++kc) {
        const bf16x8 vf = *(const bf16x8*)((const char*)Vs + cur * 16384 + rr * 128 +
                                           (((kc * 32 + g * 8) << 1) ^ sw));
        o_acc[nb2] = __builtin_amdgcn_mfma_f32_16x16x32_bf16(pf[kc], vf, o_acc[nb2], 0, 0, 0);
      }
    }
    __builtin_amdgcn_s_setprio(0);

    if (t < 15) {
      asm volatile("s_waitcnt vmcnt(0)" ::: "memory");
      __syncthreads();
    }
    cur ^= 1;
  }

  // epilogue: finish l reduce, normalize, packed write + zero pad (attn_arrange fused)
  l_run += __shfl_xor(l_run, 16);
  l_run += __shfl_xor(l_run, 32);
  float rl[4];
#pragma unroll
  for (int r = 0; r < 4; ++r)
    rl[r] = 1.0f / __shfl(l_run, (lane & 48) | (((lane >> 4) & 3) << 2) | r);
  const int d_b = 32 * (cfg[b] + 1);   // D_LIST = {32,64,96,128}
  const int zw = 128 - d_b;
  const size_t rowbase = (size_t)(b * 1024 + q0 + w * 16 + g * 4);
#pragma unroll
  for (int nb2 = 0; nb2 < 8; ++nb2) {
    const int dk = nb2 * 16 + ln;
    if (dk < d_b) {
#pragma unroll
      for (int r = 0; r < 4; r++)
        ret[(rowbase + r) * 1024 + h * d_b + dk] = f2bf(o_acc[nb2][r] * rl[r]);
    } else {
#pragma unroll
      for (int r = 0; r < 4; r++)
        ret[(rowbase + r) * 1024 + 8 * d_b + h * zw + (dk - d_b)] = 0;
    }
  }
}

// ---------------- launch ----------------
extern "C" void kernel_launch(void* const* d_in, const int* in_sizes, int n_in,
                              void* d_out, int out_size, void* d_ws, size_t ws_size,
                              hipStream_t stream)
{
  (void)in_sizes; (void)n_in; (void)out_size; (void)ws_size;
  const float* q   = (const float*)d_in[0];
  const float* k   = (const float*)d_in[1];
  const float* v   = (const float*)d_in[2];
  const int*   cfg = (const int*)d_in[3];
  const float* Wq  = (const float*)d_in[4];  const float* bq = (const float*)d_in[5];
  const float* Wk  = (const float*)d_in[6];  const float* bk = (const float*)d_in[7];
  const float* Wv  = (const float*)d_in[8];  const float* bv = (const float*)d_in[9];
  const float* Wo  = (const float*)d_in[10]; const float* bo = (const float*)d_in[11];

  const size_t X  = 8192ull * 1024ull;
  const size_t WN = 1024ull * 1024ull;
  char* p = (char*)d_ws;
  unsigned short* xq  = (unsigned short*)p; p += X * 2;
  unsigned short* xk  = (unsigned short*)p; p += X * 2;
  unsigned short* xv  = (unsigned short*)p; p += X * 2;
  unsigned short* wb  = (unsigned short*)p; p += 4 * WN * 2;
  unsigned short* Qp  = (unsigned short*)p; p += X * 2;
  unsigned short* Kp  = (unsigned short*)p; p += X * 2;
  unsigned short* VTp = (unsigned short*)p; p += X * 2;
  unsigned short* ret = (unsigned short*)p; p += X * 2;

  convert_kernel<<<dim3(8192), dim3(256), 0, stream>>>(q, k, v, Wq, Wk, Wv, Wo,
                                                       xq, xk, xv, wb);

  gemm8p<<<dim3(384), dim3(512), 0, stream>>>(xq, xk, xv, wb, bq, bk, bv,
                                              Qp, Kp, VTp);

  attn_kernel<<<dim3(512), dim3(512), 0, stream>>>(Qp, Kp, VTp, cfg, ret);

  gemm_out<<<dim3(512), dim3(256), 0, stream>>>(ret, wb + 3 * WN, bo, (float*)d_out);
}

// Round 10
// 171.511 us; speedup vs baseline: 1.1863x; 1.0301x over previous
//
#include <hip/hip_runtime.h>
#include <hip/hip_bf16.h>

// Fused MHA, B=8, S=1024, H=8, DK=128, D=1024, fp32 in/out, bf16 MFMA compute.
// convert -> QKV proj (256x128 3-buffer lead-2 counted-vmcnt GEMM, 768 blocks =
// 3 exact rounds, merged z=3, XCD swizzle, V^T epilogue) -> flash attn (QBLK=128,
// swapped-QK in-lane softmax, cvt_pk, XCD swizzle, fused attn_arrange) ->
// out proj (same GEMM, 256 blocks = 1 exact round, fp32 out).

typedef __attribute__((ext_vector_type(8))) __bf16 bf16x8;
typedef __attribute__((ext_vector_type(4))) float f32x4;

#define DEV static __device__ __forceinline__

DEV float exp2v(float x) { return __builtin_amdgcn_exp2f(x); }

DEV unsigned short f2bf(float f) {
  union { float f; unsigned int u; } c; c.f = f;
  unsigned int u = c.u + 0x7fffu + ((c.u >> 16) & 1u);
  return (unsigned short)(u >> 16);
}

DEV unsigned cvtpk(float a, float b) {
  unsigned r;
  asm("v_cvt_pk_bf16_f32 %0, %1, %2" : "=v"(r) : "v"(a), "v"(b));
  return r;
}

DEV void gload16(const void* g, void* l) {
  __builtin_amdgcn_global_load_lds((const __attribute__((address_space(1))) void*)g,
                                   (__attribute__((address_space(3))) void*)l, 16, 0, 0);
}

#define LGKM0 asm volatile("s_waitcnt lgkmcnt(0)" ::: "memory")
#define BAR   __builtin_amdgcn_s_barrier()
#define VMC6  asm volatile("s_waitcnt vmcnt(6)" ::: "memory")
#define VMC0  asm volatile("s_waitcnt vmcnt(0)" ::: "memory")

// ---------------- convert: fp32->bf16 ----------------
DEV void cv4(const float* __restrict__ s, unsigned short* __restrict__ d, int i) {
  const float4 a = *(const float4*)(s + i);
  ushort4 o;
  o.x = f2bf(a.x); o.y = f2bf(a.y); o.z = f2bf(a.z); o.w = f2bf(a.w);
  *(ushort4*)(d + i) = o;
}

__global__ __launch_bounds__(256) void convert_kernel(
    const float* __restrict__ q, const float* __restrict__ k, const float* __restrict__ v,
    const float* __restrict__ wq, const float* __restrict__ wk,
    const float* __restrict__ wv, const float* __restrict__ wo,
    unsigned short* __restrict__ xq, unsigned short* __restrict__ xk,
    unsigned short* __restrict__ xv, unsigned short* __restrict__ wb)
{
  const int i = (blockIdx.x * 256 + threadIdx.x) * 4;
  cv4(q, xq, i);
  cv4(k, xk, i);
  cv4(v, xv, i);
  if (i < 4 * 1024 * 1024) {
    const int which = i >> 20, off = i & 1048575;
    const float* s = which == 0 ? wq : which == 1 ? wk : which == 2 ? wv : wo;
    cv4(s, wb + (which << 20), off);
  }
}

// ---------------- 256x128 3-buffer lead-2 counted-vmcnt GEMM ----------------
// C[m,n] = sum_k A[m,k]*Bt[n,k] + bias[n]. K=1024 = 16 BK=64 tiles.
// 512 thr = 8 waves (4M x 2N), per-wave 64x64 (acc[4][4]).
// LDS 144 KiB: A 3buf x 256x128B @0; B 3buf x 128x128B @98304. T2 XOR swizzle.
// Per tile t (2 phases x 16 MFMA): ph0 {rdB, rdA(q0) | stage A(t+2) | BAR lgkm0
// mm(0) BAR}; ph1 {rdA(q1) | stage B(t+2) | BAR lgkm0 mm(1) | gate VMC(6) BAR}.
// Ledger: 6 loads/tile, lead 2 => exactly t+2's 6 loads younger at each gate.
// OUTMODE 0: QKV merged (z: 0=Q scaled, 1=K, 2=V^T packed), 768 blocks.
// OUTMODE 1: fp32 out (out projection), 256 blocks.
template<int OUTMODE>
__global__ __launch_bounds__(512, 1) void gemmS(
    const unsigned short* __restrict__ xq, const unsigned short* __restrict__ xk,
    const unsigned short* __restrict__ xv, const unsigned short* __restrict__ wb,
    const float* __restrict__ bq, const float* __restrict__ bk,
    const float* __restrict__ bv,
    unsigned short* __restrict__ Qp, unsigned short* __restrict__ Kp,
    unsigned short* __restrict__ VTp, float* __restrict__ fout)
{
  __shared__ __align__(16) char LDS[147456];
  int z, mt, nt;
  if (OUTMODE == 0) {        // 768 blocks = 8 XCD x 96
    const int swz = (blockIdx.x & 7) * 96 + (blockIdx.x >> 3);
    z = swz >> 8; const int rem = swz & 255; mt = rem >> 3; nt = rem & 7;
  } else {                   // 256 blocks = 8 XCD x 32
    const int swz = (blockIdx.x & 7) * 32 + (blockIdx.x >> 3);
    z = 0; mt = swz >> 3; nt = swz & 7;
  }
  const int m0 = mt * 256, n0 = nt * 128;
  const unsigned short* Ag = (OUTMODE == 1) ? xq : (z == 0 ? xq : z == 1 ? xk : xv);
  const unsigned short* Bg = (OUTMODE == 1) ? wb : wb + ((size_t)z << 20);
  const float* bias = (OUTMODE == 1) ? bq : (z == 0 ? bq : z == 1 ? bk : bv);

  const int tid = threadIdx.x, lane = tid & 63, w = tid >> 6;
  const int wm = w >> 1, wn = w & 1;      // 4M x 2N wave grid
  const int g = lane >> 4, ln = lane & 15;

  const f32x4 fzero = {0.f, 0.f, 0.f, 0.f};
  f32x4 acc[4][4];
#pragma unroll
  for (int i = 0; i < 4; i++)
#pragma unroll
    for (int j = 0; j < 4; j++) acc[i][j] = fzero;

  bf16x8 bfr[4][2];   // B frags persist per K-tile
  bf16x8 afr[2][2];   // A mfrag-pair, transient per phase

  // stage A half-tile (128 rows x 128B): 2 loads/thread; linear dest,
  // inverse-swizzled global source (T2 both-sides involution).
  auto SA = [&](int bf, int hf, int k0) {
    const unsigned short* src = Ag + (size_t)(m0 + hf * 128) * 1024 + k0;
    char* base = LDS + bf * 32768 + hf * 16384 + w * 2048;
#pragma unroll
    for (int r2 = 0; r2 < 2; ++r2) {
      const int o = w * 2048 + r2 * 1024 + lane * 16;
      const int rwi = o >> 7, cb = o & 127;
      gload16(src + (size_t)rwi * 1024 + ((cb ^ ((rwi & 7) << 4)) >> 1), base + r2 * 1024);
    }
  };
  // stage B tile (128 rows x 128B): 2 loads/thread
  auto SB = [&](int bf, int k0) {
    const unsigned short* src = Bg + (size_t)n0 * 1024 + k0;
    char* base = LDS + 98304 + bf * 16384 + w * 2048;
#pragma unroll
    for (int r2 = 0; r2 < 2; ++r2) {
      const int o = w * 2048 + r2 * 1024 + lane * 16;
      const int rwi = o >> 7, cb = o & 127;
      gload16(src + (size_t)rwi * 1024 + ((cb ^ ((rwi & 7) << 4)) >> 1), base + r2 * 1024);
    }
  };
  auto rdA = [&](int bf, int q) {
#pragma unroll
    for (int p = 0; p < 2; ++p) {
      const int row = wm * 64 + (2 * q + p) * 16 + ln;
      const int sw = (row & 7) << 4;
#pragma unroll
      for (int kc = 0; kc < 2; ++kc)
        afr[p][kc] = *(const bf16x8*)(LDS + bf * 32768 + row * 128 + ((kc * 64 + g * 16) ^ sw));
    }
  };
  auto rdB = [&](int bf) {
#pragma unroll
    for (int nf = 0; nf < 4; ++nf) {
      const int row = wn * 64 + nf * 16 + ln;
      const int sw = (row & 7) << 4;
#pragma unroll
      for (int kc = 0; kc < 2; ++kc)
        bfr[nf][kc] = *(const bf16x8*)(LDS + 98304 + bf * 16384 + row * 128 + ((kc * 64 + g * 16) ^ sw));
    }
  };
  auto mm = [&](int q) {
    __builtin_amdgcn_s_setprio(1);
#pragma unroll
    for (int p = 0; p < 2; ++p)
#pragma unroll
      for (int nf = 0; nf < 4; ++nf)
#pragma unroll
        for (int kc = 0; kc < 2; ++kc)
          acc[2 * q + p][nf] =
              __builtin_amdgcn_mfma_f32_16x16x32_bf16(afr[p][kc], bfr[nf][kc],
                                                      acc[2 * q + p][nf], 0, 0, 0);
    __builtin_amdgcn_s_setprio(0);
  };

  // prologue: tiles 0,1 fully staged (12 loads); gate leaves tile1's 6 in flight
  SA(0, 0, 0); SA(0, 1, 0); SB(0, 0);
  SA(1, 0, 64); SA(1, 1, 64); SB(1, 64);
  VMC6; BAR;

  int br = 0, bw = 2;
  for (int t = 0; t < 16; ++t) {
    const int kL = (t + 2) << 6;
    // ph0: read B + A(q0) of tile t; stage A(t+2)
    rdB(br); rdA(br, 0);
    if (t < 14) { SA(bw, 0, kL); SA(bw, 1, kL); }
    BAR; LGKM0; mm(0); BAR;
    // ph1: read A(q1); stage B(t+2); gate for tile t+1
    rdA(br, 1);
    if (t < 14) SB(bw, kL);
    BAR; LGKM0; mm(1);
    if (t < 14) { VMC6; } else if (t == 14) { VMC0; }
    BAR;
    br = br == 2 ? 0 : br + 1;
    bw = bw == 2 ? 0 : bw + 1;
  }

  // epilogue
  const float QS = 0.12751743f;   // 1/sqrt(128)*log2(e)
#pragma unroll
  for (int mf = 0; mf < 4; ++mf)
#pragma unroll
    for (int nf = 0; nf < 4; ++nf) {
      const int m = m0 + wm * 64 + mf * 16 + g * 4;
      const int n = n0 + wn * 64 + nf * 16 + ln;
      const float bn = bias[n];
      if (OUTMODE == 1) {
#pragma unroll
        for (int r = 0; r < 4; ++r)
          fout[(size_t)(m + r) * 1024 + n] = acc[mf][nf][r] + bn;
      } else if (z == 0) {
#pragma unroll
        for (int r = 0; r < 4; ++r)
          Qp[(size_t)(m + r) * 1024 + n] = f2bf((acc[mf][nf][r] + bn) * QS);
      } else if (z == 1) {
#pragma unroll
        for (int r = 0; r < 4; ++r)
          Kp[(size_t)(m + r) * 1024 + n] = f2bf(acc[mf][nf][r] + bn);
      } else {
        const int b = m >> 10, s0 = m & 1023;   // n = h*128+dk
        uint2 pk;
        pk.x = cvtpk(acc[mf][nf][0] + bn, acc[mf][nf][1] + bn);
        pk.y = cvtpk(acc[mf][nf][2] + bn, acc[mf][nf][3] + bn);
        *(uint2*)(VTp + (((size_t)(b * 1024 + n)) << 10) + s0) = pk;
      }
    }
}

// ---------------- flash attention + fused attn_arrange (+zero pad) ----------------
// Grid 512 = 8 qb x 64 (b,h); XCD-coherent. 512 thr = 8 waves x 16 q-rows (QBLK 128).
__global__ __launch_bounds__(512) void attn_kernel(
    const unsigned short* __restrict__ Qp, const unsigned short* __restrict__ Kp,
    const unsigned short* __restrict__ VT, const int* __restrict__ cfg,
    unsigned short* __restrict__ ret)
{
  __shared__ __align__(16) unsigned short Ks[2][64 * 128];
  __shared__ __align__(16) unsigned short Vs[2][128 * 64];
  __shared__ __align__(16) unsigned short Ps[8 * 16 * 64];
  const int bx = blockIdx.x;
  const int qb = bx >> 6, bh = bx & 63, b = bh >> 3, h = bh & 7;
  const int tid = threadIdx.x, lane = tid & 63, w = tid >> 6;
  const int g = lane >> 4, ln = lane & 15;
  const int q0 = qb * 128;
  const f32x4 fzero = {0.f, 0.f, 0.f, 0.f};

  bf16x8 qf[4];
  {
    const unsigned short* qrow = Qp + ((size_t)(b * 1024 + q0 + w * 16 + ln)) * 1024 + h * 128;
#pragma unroll
    for (int kc = 0; kc < 4; kc++) qf[kc] = *(const bf16x8*)(qrow + kc * 32 + g * 8);
  }
  float m_run = -1e30f, l_run = 0.f;
  f32x4 o_acc[8];
#pragma unroll
  for (int i = 0; i < 8; i++) o_acc[i] = fzero;

  auto stage = [&](int buf, int kv0) {
#pragma unroll
    for (int i = 0; i < 2; ++i) {
      const int o = i * 8192 + tid * 16;
      {
        const int r = o >> 8, cb = o & 255;
        const int cs = cb ^ ((r & 7) << 4);
        gload16(Kp + ((size_t)(b * 1024 + kv0 + r)) * 1024 + h * 128 + (cs >> 1),
                (char*)Ks + buf * 16384 + o);
      }
      {
        const int r = o >> 7, cb = o & 127;
        const int cs = cb ^ ((r & 7) << 4);
        gload16(VT + ((size_t)((b * 8 + h) * 128 + r)) * 1024 + kv0 + (cs >> 1),
                (char*)Vs + buf * 16384 + o);
      }
    }
  };

  stage(0, 0);
  asm volatile("s_waitcnt vmcnt(0)" ::: "memory");
  __syncthreads();

  int cur = 0;
  for (int t = 0; t < 16; ++t) {
    if (t < 15) stage(cur ^ 1, (t + 1) * 64);

    f32x4 sc[4];
    __builtin_amdgcn_s_setprio(1);
#pragma unroll
    for (int nb = 0; nb < 4; ++nb) {
      sc[nb] = fzero;
      const int rr = nb * 16 + ln;
      const int sw = (rr & 7) << 4;
#pragma unroll
      for (int kc = 0; kc < 4; ++kc) {
        const bf16x8 kf = *(const bf16x8*)((const char*)Ks + cur * 16384 + rr * 256 +
                                           (((kc * 32 + g * 8) << 1) ^ sw));
        sc[nb] = __builtin_amdgcn_mfma_f32_16x16x32_bf16(kf, qf[kc], sc[nb], 0, 0, 0);
      }
    }
    __builtin_amdgcn_s_setprio(0);

    float mnb[4];
#pragma unroll
    for (int nb = 0; nb < 4; ++nb)
      mnb[nb] = fmaxf(fmaxf(sc[nb][0], sc[nb][1]), fmaxf(sc[nb][2], sc[nb][3]));
    float pmax = fmaxf(fmaxf(mnb[0], mnb[1]), fmaxf(mnb[2], mnb[3]));
    pmax = fmaxf(pmax, __shfl_xor(pmax, 16));
    pmax = fmaxf(pmax, __shfl_xor(pmax, 32));
    if (__any(pmax > m_run + 11.5f)) {
      const float mnew = fmaxf(m_run, pmax);
      const float alpha = exp2v(m_run - mnew);
      l_run *= alpha;
      m_run = mnew;
      float ar[4];
#pragma unroll
      for (int r = 0; r < 4; ++r)
        ar[r] = __shfl(alpha, (lane & 48) | (((lane >> 4) & 3) << 2) | r);
#pragma unroll
      for (int i = 0; i < 8; i++)
#pragma unroll
        for (int r = 0; r < 4; r++) o_acc[i][r] *= ar[r];
    }
    float sum = 0.f;
    float pvv[16];
#pragma unroll
    for (int nb = 0; nb < 4; ++nb)
#pragma unroll
      for (int r = 0; r < 4; ++r) {
        const float p = exp2v(sc[nb][r] - m_run);
        pvv[nb * 4 + r] = p; sum += p;
      }
    l_run += sum;

    {
      char* pbase = (char*)Ps + w * 2048 + ln * 128;
#pragma unroll
      for (int nb = 0; nb < 4; ++nb) {
        uint2 pk;
        pk.x = cvtpk(pvv[nb * 4 + 0], pvv[nb * 4 + 1]);
        pk.y = cvtpk(pvv[nb * 4 + 2], pvv[nb * 4 + 3]);
        *(uint2*)(pbase + (((16 * nb + 4 * g) << 1) ^ ((ln & 7) << 4))) = pk;
      }
    }
    bf16x8 pf[2];
#pragma unroll
    for (int kc = 0; kc < 2; kc++)
      pf[kc] = *(const bf16x8*)((const char*)Ps + w * 2048 + ln * 128 +
                                (((kc * 32 + g * 8) << 1) ^ ((ln & 7) << 4)));

    __builtin_amdgcn_s_setprio(1);
#pragma unroll
    for (int nb2 = 0; nb2 < 8; ++nb2) {
      const int rr = nb2 * 16 + ln;
      const int sw = (rr & 7) << 4;
#pragma unroll
      for (int kc = 0; kc < 2; ++kc) {
        const bf16x8 vf = *(const bf16x8*)((const char*)Vs + cur * 16384 + rr * 128 +
                                           (((kc * 32 + g * 8) << 1) ^ sw));
        o_acc[nb2] = __builtin_amdgcn_mfma_f32_16x16x32_bf16(pf[kc], vf, o_acc[nb2], 0, 0, 0);
      }
    }
    __builtin_amdgcn_s_setprio(0);

    if (t < 15) {
      asm volatile("s_waitcnt vmcnt(0)" ::: "memory");
      __syncthreads();
    }
    cur ^= 1;
  }

  l_run += __shfl_xor(l_run, 16);
  l_run += __shfl_xor(l_run, 32);
  float rl[4];
#pragma unroll
  for (int r = 0; r < 4; ++r)
    rl[r] = 1.0f / __shfl(l_run, (lane & 48) | (((lane >> 4) & 3) << 2) | r);
  const int d_b = 32 * (cfg[b] + 1);
  const int zw = 128 - d_b;
  const size_t rowbase = (size_t)(b * 1024 + q0 + w * 16 + g * 4);
#pragma unroll
  for (int nb2 = 0; nb2 < 8; ++nb2) {
    const int dk = nb2 * 16 + ln;
    if (dk < d_b) {
#pragma unroll
      for (int r = 0; r < 4; r++)
        ret[(rowbase + r) * 1024 + h * d_b + dk] = f2bf(o_acc[nb2][r] * rl[r]);
    } else {
#pragma unroll
      for (int r = 0; r < 4; r++)
        ret[(rowbase + r) * 1024 + 8 * d_b + h * zw + (dk - d_b)] = 0;
    }
  }
}

// ---------------- launch ----------------
extern "C" void kernel_launch(void* const* d_in, const int* in_sizes, int n_in,
                              void* d_out, int out_size, void* d_ws, size_t ws_size,
                              hipStream_t stream)
{
  (void)in_sizes; (void)n_in; (void)out_size; (void)ws_size;
  const float* q   = (const float*)d_in[0];
  const float* k   = (const float*)d_in[1];
  const float* v   = (const float*)d_in[2];
  const int*   cfg = (const int*)d_in[3];
  const float* Wq  = (const float*)d_in[4];  const float* bq = (const float*)d_in[5];
  const float* Wk  = (const float*)d_in[6];  const float* bk = (const float*)d_in[7];
  const float* Wv  = (const float*)d_in[8];  const float* bv = (const float*)d_in[9];
  const float* Wo  = (const float*)d_in[10]; const float* bo = (const float*)d_in[11];

  const size_t X  = 8192ull * 1024ull;
  const size_t WN = 1024ull * 1024ull;
  char* p = (char*)d_ws;
  unsigned short* xq  = (unsigned short*)p; p += X * 2;
  unsigned short* xk  = (unsigned short*)p; p += X * 2;
  unsigned short* xv  = (unsigned short*)p; p += X * 2;
  unsigned short* wb  = (unsigned short*)p; p += 4 * WN * 2;
  unsigned short* Qp  = (unsigned short*)p; p += X * 2;
  unsigned short* Kp  = (unsigned short*)p; p += X * 2;
  unsigned short* VTp = (unsigned short*)p; p += X * 2;
  unsigned short* ret = (unsigned short*)p; p += X * 2;

  convert_kernel<<<dim3(8192), dim3(256), 0, stream>>>(q, k, v, Wq, Wk, Wv, Wo,
                                                       xq, xk, xv, wb);

  gemmS<0><<<dim3(768), dim3(512), 0, stream>>>(xq, xk, xv, wb, bq, bk, bv,
                                                Qp, Kp, VTp, nullptr);

  attn_kernel<<<dim3(512), dim3(512), 0, stream>>>(Qp, Kp, VTp, cfg, ret);

  gemmS<1><<<dim3(256), dim3(512), 0, stream>>>(ret, nullptr, nullptr, wb + 3 * WN,
                                                bo, nullptr, nullptr,
                                                nullptr, nullptr, nullptr,
                                                (float*)d_out);
}